// Round 18
// baseline (401.475 us; speedup 1.0000x reference)
//
#include <hip/hip_runtime.h>
#include <hip/hip_fp16.h>
#include <math.h>

constexpr float NEG_SLOPE = 0.2f;
constexpr float BN_EPS_C = 1e-5f;

using half8 = __attribute__((ext_vector_type(8))) _Float16;
using half4 = __attribute__((ext_vector_type(4))) _Float16;
using f32x4 = __attribute__((ext_vector_type(4))) float;

// ================= CSR build: LDS-binned two-level counting sort =================

__global__ __launch_bounds__(256)
void hist_cvt_kernel(const int* __restrict__ ei, int* __restrict__ bucket_count,
                     int E, int N, int NEB,
                     const float* __restrict__ W0, const float* __restrict__ W1,
                     const float* __restrict__ W2,
                     __half* __restrict__ W0h, __half* __restrict__ W1h,
                     __half* __restrict__ W2h) {
    int t = threadIdx.x;
    if ((int)blockIdx.x >= NEB) {
        int i = ((int)blockIdx.x - NEB) * 256 + t;
        if (i < 16384) {
            W0h[i] = __float2half(W0[i]);
            W1h[i] = __float2half(W1[i]);
        }
        if (i < 6144) W2h[i] = __float2half(i < 5120 ? W2[i] : 0.f);
        return;
    }
    __shared__ int h[256];
    h[t] = 0;
    __syncthreads();
    int base = blockIdx.x * 8192;
    int ET = E + N;
#pragma unroll
    for (int q = 0; q < 32; ++q) {
        int i = base + q * 256 + t;
        if (i < ET) {
            int d = (i < E) ? ei[E + i] : (i - E);
            atomicAdd(&h[d >> 8], 1);
        }
    }
    __syncthreads();
    if (h[t] > 0) atomicAdd(&bucket_count[t], h[t]);
}

__global__ __launch_bounds__(256)
void bucket_scan_kernel(const int* __restrict__ bucket_count, int* __restrict__ bucket_ptr,
                        int* __restrict__ gcursor, int* __restrict__ row_ptr,
                        int N, int ET) {
    __shared__ int s[256];
    int t = threadIdx.x;
    int c = bucket_count[t];
    s[t] = c;
    __syncthreads();
    for (int off = 1; off < 256; off <<= 1) {
        int v = (t >= off) ? s[t - off] : 0;
        __syncthreads();
        s[t] += v;
        __syncthreads();
    }
    int excl = s[t] - c;
    bucket_ptr[t] = excl;
    gcursor[t] = excl;
    if (t == 255) {
        bucket_ptr[256] = s[255];
        row_ptr[N] = ET;
    }
}

__global__ __launch_bounds__(256)
void bucket_bin_kernel(const int* __restrict__ ei, int* __restrict__ gcursor,
                       unsigned* __restrict__ tmp, int E, int N) {
    __shared__ unsigned bins[8192];
    __shared__ int lcount[256];
    __shared__ int lofs[256];
    __shared__ int lbase[256];
    __shared__ int lcur[256];
    int t = threadIdx.x;
    lcount[t] = 0;
    __syncthreads();
    int base = blockIdx.x * 8192;
    int ET = E + N;
    unsigned pr[32];
#pragma unroll
    for (int q = 0; q < 32; ++q) {
        int i = base + q * 256 + t;
        pr[q] = 0xFFFFFFFFu;
        if (i < ET) {
            int s, d;
            if (i < E) { s = ei[i]; d = ei[E + i]; }
            else       { s = i - E; d = s; }
            pr[q] = ((unsigned)d << 16) | (unsigned)s;
            atomicAdd(&lcount[d >> 8], 1);
        }
    }
    __syncthreads();
    {
        int c = lcount[t];
        lofs[t] = c;
        __syncthreads();
        for (int off = 1; off < 256; off <<= 1) {
            int v = (t >= off) ? lofs[t - off] : 0;
            __syncthreads();
            lofs[t] += v;
            __syncthreads();
        }
        int excl = lofs[t] - c;
        __syncthreads();
        lofs[t] = excl;
        lcur[t] = excl;
        if (c > 0) lbase[t] = atomicAdd(&gcursor[t], c);
    }
    __syncthreads();
#pragma unroll
    for (int q = 0; q < 32; ++q) {
        if (pr[q] != 0xFFFFFFFFu) {
            int b = pr[q] >> 24;
            int p = atomicAdd(&lcur[b], 1);
            bins[p] = pr[q];
        }
    }
    __syncthreads();
    int total = min(8192, ET - base);
    for (int p = t; p < total; p += 256) {
        unsigned e = bins[p];
        int b = e >> 24;
        tmp[lbase[b] + (p - lofs[b])] = e;
    }
}

__global__ __launch_bounds__(256)
void fine_scatter_kernel(const unsigned* __restrict__ tmp, const int* __restrict__ bucket_ptr,
                         int* __restrict__ row_ptr, int* __restrict__ srcs, int N) {
    __shared__ int hist[256];
    __shared__ int scanb[256];
    __shared__ int cur[256];
    int b = blockIdx.x, t = threadIdx.x;
    int base = bucket_ptr[b];
    int cnt = bucket_ptr[b + 1] - base;
    int n0 = b << 8;
    hist[t] = 0;
    __syncthreads();
    for (int p = t; p < cnt; p += 256)
        atomicAdd(&hist[(int)(tmp[base + p] >> 16) - n0], 1);
    __syncthreads();
    int c = hist[t];
    scanb[t] = c;
    __syncthreads();
    for (int off = 1; off < 256; off <<= 1) {
        int v = (t >= off) ? scanb[t - off] : 0;
        __syncthreads();
        scanb[t] += v;
        __syncthreads();
    }
    int excl = scanb[t] - c;
    cur[t] = excl;
    if (n0 + t < N) row_ptr[n0 + t] = base + excl;
    __syncthreads();
    for (int p = t; p < cnt; p += 256) {
        unsigned e = tmp[base + p];
        int pos = atomicAdd(&cur[(int)(e >> 16) - n0], 1);
        srcs[base + pos] = (int)(e & 0xFFFFu);
    }
}

// ---------------- MFMA GEMM 128: h(fp16, slice-major) + alphas [N][8] ----------

template<bool AHALF>
__global__ __launch_bounds__(512)
void gemm128_mfma_kernel(const void* __restrict__ Xv, const __half* __restrict__ W16,
                         const float* __restrict__ a_src, const float* __restrict__ a_dst,
                         __half* __restrict__ hp, float* __restrict__ asrc,
                         float* __restrict__ adst, int N) {
    __shared__ _Float16 Bs[128][136];
    const int t = threadIdx.x;
    const int n0 = blockIdx.x * 128;

#pragma unroll
    for (int i = 0; i < 4; ++i) {
        int lin = t + i * 512;
        int n = lin >> 4;
        int m = lin & 15;
        *reinterpret_cast<uint4*>(&Bs[n][8 * m]) =
            *reinterpret_cast<const uint4*>(&W16[(size_t)n * 128 + 8 * m]);
    }
    __syncthreads();

    const int l  = t & 63;
    const int w  = t >> 6;
    const int lr = l & 15;
    const int lg = l >> 4;
    const int rowA = n0 + 16 * w + lr;
    const bool rokA = rowA < N;

    f32x4 acc[8];
#pragma unroll
    for (int tt = 0; tt < 8; ++tt) acc[tt] = (f32x4){0.f, 0.f, 0.f, 0.f};

#pragma unroll
    for (int ks = 0; ks < 4; ++ks) {
        half8 a;
        if (rokA) {
            if constexpr (AHALF) {
                const __half* X = (const __half*)Xv;   // slice-major [8][N][16]
                int ch = 8 * lg + 32 * ks;
                int sl = ch >> 4;
                int off = ch & 15;
                a = *reinterpret_cast<const half8*>(
                    &X[(size_t)sl * N * 16 + (size_t)rowA * 16 + off]);
            } else {
                const float* X = (const float*)Xv;
                const float* p = &X[(size_t)rowA * 128 + 8 * lg + 32 * ks];
                float4 v0 = *reinterpret_cast<const float4*>(p);
                float4 v1 = *reinterpret_cast<const float4*>(p + 4);
                a[0] = (_Float16)v0.x; a[1] = (_Float16)v0.y;
                a[2] = (_Float16)v0.z; a[3] = (_Float16)v0.w;
                a[4] = (_Float16)v1.x; a[5] = (_Float16)v1.y;
                a[6] = (_Float16)v1.z; a[7] = (_Float16)v1.w;
            }
        } else {
#pragma unroll
            for (int q = 0; q < 8; ++q) a[q] = (_Float16)0.f;
        }
#pragma unroll
        for (int tt = 0; tt < 8; ++tt) {
            half8 b = *reinterpret_cast<const half8*>(&Bs[16 * tt + lr][8 * lg + 32 * ks]);
            acc[tt] = __builtin_amdgcn_mfma_f32_16x16x32_f16(a, b, acc[tt], 0, 0, 0);
        }
    }

    float av[8], bv[8];
#pragma unroll
    for (int tt = 0; tt < 8; ++tt) {
        av[tt] = a_src[16 * tt + lr];
        bv[tt] = a_dst[16 * tt + lr];
    }
#pragma unroll
    for (int reg = 0; reg < 4; ++reg) {
        int gr = n0 + 16 * w + 4 * lg + reg;
        bool ok = gr < N;
        if (ok) {
#pragma unroll
            for (int tt = 0; tt < 8; ++tt)
                hp[(size_t)tt * N * 16 + (size_t)gr * 16 + lr] = __float2half(acc[tt][reg]);
        }
#pragma unroll
        for (int tt = 0; tt < 8; ++tt) {
            float p = acc[tt][reg] * av[tt];
            float q = acc[tt][reg] * bv[tt];
#pragma unroll
            for (int off = 1; off < 16; off <<= 1) {
                p += __shfl_xor(p, off, 16);
                q += __shfl_xor(q, off, 16);
            }
            if (ok && lr == tt) {        // alphas packed [N][8]
                asrc[(size_t)gr * 8 + tt] = p;
                adst[(size_t)gr * 8 + tt] = q;
            }
        }
    }
}

// ---------------- MFMA GEMM 40 (A slice-major): h2(fp16 [N][40]) + flat alphas ----------

__global__ __launch_bounds__(256)
void gemm40_mfma_kernel(const __half* __restrict__ X, const __half* __restrict__ W16,
                        const float* __restrict__ a_src, const float* __restrict__ a_dst,
                        __half* __restrict__ hp, float* __restrict__ asrc,
                        float* __restrict__ adst, int N) {
    __shared__ _Float16 Bs[48][136];
    const int t = threadIdx.x;
    const int n0 = blockIdx.x * 64;

#pragma unroll
    for (int i = 0; i < 3; ++i) {
        int lin = t + i * 256;
        if (lin < 768) {
            int n = lin >> 4;
            int m = lin & 15;
            *reinterpret_cast<uint4*>(&Bs[n][8 * m]) =
                *reinterpret_cast<const uint4*>(&W16[(size_t)n * 128 + 8 * m]);
        }
    }
    __syncthreads();

    const int l  = t & 63;
    const int w  = t >> 6;
    const int lr = l & 15;
    const int lg = l >> 4;
    const int rowA = n0 + 16 * w + lr;
    const bool rokA = rowA < N;

    f32x4 acc[3];
#pragma unroll
    for (int tt = 0; tt < 3; ++tt) acc[tt] = (f32x4){0.f, 0.f, 0.f, 0.f};

#pragma unroll
    for (int ks = 0; ks < 4; ++ks) {
        half8 a;
        if (rokA) {
            int ch = 8 * lg + 32 * ks;
            int sl = ch >> 4;
            int off = ch & 15;
            a = *reinterpret_cast<const half8*>(
                &X[(size_t)sl * N * 16 + (size_t)rowA * 16 + off]);
        } else {
#pragma unroll
            for (int q = 0; q < 8; ++q) a[q] = (_Float16)0.f;
        }
#pragma unroll
        for (int tt = 0; tt < 3; ++tt) {
            half8 b = *reinterpret_cast<const half8*>(&Bs[16 * tt + lr][8 * lg + 32 * ks]);
            acc[tt] = __builtin_amdgcn_mfma_f32_16x16x32_f16(a, b, acc[tt], 0, 0, 0);
        }
    }

    float av[3], bv[3];
#pragma unroll
    for (int tt = 0; tt < 3; ++tt) {
        int j = 16 * tt + lr;
        av[tt] = (j < 40) ? a_src[j] : 0.f;
        bv[tt] = (j < 40) ? a_dst[j] : 0.f;
    }
#pragma unroll
    for (int reg = 0; reg < 4; ++reg) {
        int gr = n0 + 16 * w + 4 * lg + reg;
        bool ok = gr < N;
        float p = 0.f, q = 0.f;
#pragma unroll
        for (int tt = 0; tt < 3; ++tt) {
            int j = 16 * tt + lr;
            if (ok && j < 40) hp[(size_t)gr * 40 + j] = __float2half(acc[tt][reg]);
            p += acc[tt][reg] * av[tt];
            q += acc[tt][reg] * bv[tt];
        }
#pragma unroll
        for (int off = 1; off < 16; off <<= 1) {
            p += __shfl_xor(p, off, 16);
            q += __shfl_xor(q, off, 16);
        }
        if (ok && lr == 0) {
            asrc[gr] = p;
            adst[gr] = q;
        }
    }
}

// ---------------- edge weights precompute, H=8; ew layout [ET][8] (16B/edge) ----------

__global__ __launch_bounds__(256)
void weight8_kernel(const int* __restrict__ row_ptr, const int* __restrict__ srcs,
                    const float* __restrict__ as8, const float* __restrict__ ad8,
                    __half* __restrict__ ew, float* __restrict__ inv, int N) {
    int gid = blockIdx.x * 256 + threadIdx.x;
    int node = gid >> 3;
    int h = gid & 7;
    if (node >= N) return;
    int beg = row_ptr[node], end = row_ptr[node + 1];
    float ad = ad8[(size_t)node * 8 + h];
    float sum = 0.f;
    for (int j = beg; j < end; ++j) {
        int s = srcs[j];
        float e = as8[(size_t)s * 8 + h] + ad;
        e = (e > 0.f) ? e : NEG_SLOPE * e;
        float w = __expf(e);
        sum += w;
        ew[(size_t)j * 8 + h] = __float2half(w);
    }
    inv[(size_t)h * N + node] = 1.0f / (sum + 1e-16f);
}

// ---------------- edge weights, H=1 (layer 2), flat ew1 ----------------

__global__ __launch_bounds__(256)
void weight1_kernel(const int* __restrict__ row_ptr, const int* __restrict__ srcs,
                    const float* __restrict__ as, const float* __restrict__ ad,
                    __half* __restrict__ ew1, float* __restrict__ inv, int N) {
    int node = blockIdx.x * 256 + threadIdx.x;
    if (node >= N) return;
    int beg = row_ptr[node], end = row_ptr[node + 1];
    float a = ad[node];
    float sum = 0.f;
    for (int j = beg; j < end; ++j) {
        int s = srcs[j];
        float e = as[s] + a;
        e = (e > 0.f) ? e : NEG_SLOPE * e;
        float w = __expf(e);
        sum += w;
        ew1[j] = __float2half(w);
    }
    inv[node] = 1.0f / (sum + 1e-16f);
}

// ---------------- message gather, F=128, XCD-sliced, edge-parallel ----------------
// slice = blockIdx & 7. Block = 8 nodes (4 waves x 2 nodes). Per node: 16 edge
// slots x 2 half-lanes (half8 = 16B gathers). Index loads coalesced per node.
// lane bits: [5]=nsub, [4:1]=edge slot e, [0]=hl.

__global__ __launch_bounds__(256)
void message128_kernel(const __half* __restrict__ hhs, const int* __restrict__ row_ptr,
                       const int* __restrict__ srcs,
                       const __half* __restrict__ ew, const float* __restrict__ inv,
                       const float* __restrict__ bias,
                       const float* __restrict__ bn_g, const float* __restrict__ bn_b,
                       const float* __restrict__ bn_m, const float* __restrict__ bn_v,
                       __half* __restrict__ feat_s, int N) {
    const int slice = blockIdx.x & 7;
    const int t = threadIdx.x;
    const int l = t & 63;
    const int node = (blockIdx.x >> 3) * 8 + (t >> 6) * 2 + (l >> 5);
    if (node >= N) return;
    const int e  = (l >> 1) & 15;
    const int hl = l & 1;
    const int beg = row_ptr[node], end = row_ptr[node + 1];
    const __half* hsl = hhs + (size_t)slice * N * 16 + 8 * hl;

    float acc[8];
#pragma unroll
    for (int k = 0; k < 8; ++k) acc[k] = 0.f;

    for (int j0 = beg; j0 < end; j0 += 16) {
        int idx = j0 + e;
        if (idx < end) {
            int s = srcs[idx];
            float wgt = __half2float(ew[(size_t)idx * 8 + slice]);
            half8 v = *reinterpret_cast<const half8*>(&hsl[(size_t)s * 16]);
#pragma unroll
            for (int k = 0; k < 8; ++k) acc[k] = fmaf((float)v[k], wgt, acc[k]);
        }
    }
    // reduce across the 16 edge slots (xor lane bits 1..4)
#pragma unroll
    for (int off = 2; off < 32; off <<= 1) {
#pragma unroll
        for (int k = 0; k < 8; ++k) acc[k] += __shfl_xor(acc[k], off);
    }

    if (e == 0) {
        float iv = inv[(size_t)slice * N + node];
        int c = slice * 16 + 8 * hl;
        float r[8];
#pragma unroll
        for (int pp = 0; pp < 2; ++pp) {
            int cc = c + 4 * pp;
            float4 bi = *reinterpret_cast<const float4*>(&bias[cc]);
            float4 g  = *reinterpret_cast<const float4*>(&bn_g[cc]);
            float4 bb = *reinterpret_cast<const float4*>(&bn_b[cc]);
            float4 mm = *reinterpret_cast<const float4*>(&bn_m[cc]);
            float4 vv = *reinterpret_cast<const float4*>(&bn_v[cc]);
            r[4 * pp + 0] = (acc[4 * pp + 0] * iv + bi.x - mm.x) * rsqrtf(vv.x + BN_EPS_C) * g.x + bb.x;
            r[4 * pp + 1] = (acc[4 * pp + 1] * iv + bi.y - mm.y) * rsqrtf(vv.y + BN_EPS_C) * g.y + bb.y;
            r[4 * pp + 2] = (acc[4 * pp + 2] * iv + bi.z - mm.z) * rsqrtf(vv.z + BN_EPS_C) * g.z + bb.z;
            r[4 * pp + 3] = (acc[4 * pp + 3] * iv + bi.w - mm.w) * rsqrtf(vv.w + BN_EPS_C) * g.w + bb.w;
        }
        half8 o;
#pragma unroll
        for (int k = 0; k < 8; ++k) {
            float rv = (r[k] > 0.f) ? r[k] : expm1f(r[k]);
            o[k] = (_Float16)rv;
        }
        *reinterpret_cast<half8*>(
            &feat_s[(size_t)slice * N * 16 + (size_t)node * 16 + 8 * hl]) = o;
    }
}

// ---------------- message gather, F=40, H=1, weight-driven ----------------

__global__ __launch_bounds__(256)
void message40_kernel(const __half* __restrict__ hh2, const int* __restrict__ row_ptr,
                      const int* __restrict__ srcs,
                      const __half* __restrict__ ew1, const float* __restrict__ inv,
                      const float* __restrict__ b2, float* __restrict__ out, int N) {
    int node = blockIdx.x * 16 + (threadIdx.x >> 4);
    if (node >= N) return;
    int tc = threadIdx.x & 15;
    int beg = row_ptr[node], end = row_ptr[node + 1];
    float acc[4] = {0.f, 0.f, 0.f, 0.f};
    int j = beg;
    for (; j + 2 <= end; j += 2) {
        int s0 = srcs[j];
        int s1 = srcs[j + 1];
        float w0 = __half2float(ew1[j]);
        float w1 = __half2float(ew1[j + 1]);
        half4 v0 = (half4){0, 0, 0, 0}, v1 = (half4){0, 0, 0, 0};
        if (tc < 10) {
            v0 = *reinterpret_cast<const half4*>(&hh2[(size_t)s0 * 40 + 4 * tc]);
            v1 = *reinterpret_cast<const half4*>(&hh2[(size_t)s1 * 40 + 4 * tc]);
        }
#pragma unroll
        for (int q = 0; q < 4; ++q) {
            acc[q] = fmaf((float)v0[q], w0, acc[q]);
            acc[q] = fmaf((float)v1[q], w1, acc[q]);
        }
    }
    if (j < end) {
        int s0 = srcs[j];
        float w0 = __half2float(ew1[j]);
        half4 v0 = (half4){0, 0, 0, 0};
        if (tc < 10) v0 = *reinterpret_cast<const half4*>(&hh2[(size_t)s0 * 40 + 4 * tc]);
#pragma unroll
        for (int q = 0; q < 4; ++q) acc[q] = fmaf((float)v0[q], w0, acc[q]);
    }
    if (tc < 10) {
        float iv = inv[node];
        int c = tc * 4;
        float4 bi = *reinterpret_cast<const float4*>(&b2[c]);
        *reinterpret_cast<float4*>(&out[(size_t)node * 40 + c]) =
            make_float4(acc[0] * iv + bi.x, acc[1] * iv + bi.y,
                        acc[2] * iv + bi.z, acc[3] * iv + bi.w);
    }
}

// ---------------- launcher ----------------

static inline char* align256(char* p) {
    return (char*)(((uintptr_t)p + 255) & ~(uintptr_t)255);
}

extern "C" void kernel_launch(void* const* d_in, const int* in_sizes, int n_in,
                              void* d_out, int out_size, void* d_ws, size_t ws_size,
                              hipStream_t stream) {
    const float* x   = (const float*)d_in[0];
    const int*   ei  = (const int*)d_in[1];
    const float* W0  = (const float*)d_in[2];
    const float* as0 = (const float*)d_in[3];
    const float* ad0 = (const float*)d_in[4];
    const float* b0  = (const float*)d_in[5];
    const float* g0  = (const float*)d_in[6];
    const float* bb0 = (const float*)d_in[7];
    const float* m0  = (const float*)d_in[8];
    const float* v0  = (const float*)d_in[9];
    const float* W1  = (const float*)d_in[10];
    const float* as1 = (const float*)d_in[11];
    const float* ad1 = (const float*)d_in[12];
    const float* b1  = (const float*)d_in[13];
    const float* g1  = (const float*)d_in[14];
    const float* bb1 = (const float*)d_in[15];
    const float* m1  = (const float*)d_in[16];
    const float* v1  = (const float*)d_in[17];
    const float* W2  = (const float*)d_in[18];
    const float* as2 = (const float*)d_in[19];
    const float* ad2 = (const float*)d_in[20];
    const float* b2  = (const float*)d_in[21];

    const int N  = in_sizes[0] / 128;
    const int E  = in_sizes[1] / 2;
    const int ET = E + N;
    const int NBUK = (N + 255) >> 8;
    const int NEB  = (ET + 8191) / 8192;

    char* wsp = (char*)d_ws;
    int* bucket_count = (int*)wsp;  wsp = align256(wsp + 256 * 4);
    int* bucket_ptr   = (int*)wsp;  wsp = align256(wsp + 257 * 4);
    int* gcursor      = (int*)wsp;  wsp = align256(wsp + 256 * 4);
    int* row_ptr      = (int*)wsp;  wsp = align256(wsp + (size_t)(N + 1) * 4);
    unsigned* tmp     = (unsigned*)wsp; wsp = align256(wsp + (size_t)ET * 4);
    int* srcs         = (int*)wsp;  wsp = align256(wsp + (size_t)ET * 4);
    __half* hh        = (__half*)wsp; wsp = align256(wsp + (size_t)N * 128 * 2);   // [8][N][16]
    __half* h2        = (__half*)wsp; wsp = align256(wsp + (size_t)N * 40 * 2);    // [N][40]
    __half* feat      = (__half*)wsp; wsp = align256(wsp + (size_t)N * 128 * 2);   // [8][N][16]
    float* asr        = (float*)wsp;  wsp = align256(wsp + (size_t)N * 8 * 4);     // [N][8]
    float* adt        = (float*)wsp;  wsp = align256(wsp + (size_t)N * 8 * 4);     // [N][8]
    __half* ew        = (__half*)wsp; wsp = align256(wsp + (size_t)ET * 8 * 2);    // [ET][8]
    __half* ew1       = (__half*)wsp; wsp = align256(wsp + (size_t)ET * 2);        // [ET]
    float* inv        = (float*)wsp;  wsp = align256(wsp + (size_t)N * 8 * 4);     // [8][N]
    __half* W0h       = (__half*)wsp; wsp = align256(wsp + 16384 * 2);
    __half* W1h       = (__half*)wsp; wsp = align256(wsp + 16384 * 2);
    __half* W2h       = (__half*)wsp; wsp = align256(wsp + 6144 * 2);

    // CSR build + weight cvt
    hipMemsetAsync(bucket_count, 0, 256 * 4, stream);
    hist_cvt_kernel<<<NEB + 64, 256, 0, stream>>>(ei, bucket_count, E, N, NEB,
                                                  W0, W1, W2, W0h, W1h, W2h);
    bucket_scan_kernel<<<1, 256, 0, stream>>>(bucket_count, bucket_ptr, gcursor, row_ptr, N, ET);
    bucket_bin_kernel<<<NEB, 256, 0, stream>>>(ei, gcursor, tmp, E, N);
    fine_scatter_kernel<<<NBUK, 256, 0, stream>>>(tmp, bucket_ptr, row_ptr, srcs, N);

    const int g128 = (N + 127) / 128;
    const int g64  = (N + 63) / 64;
    const int gw8  = (N * 8 + 255) / 256;
    const int gw1  = (N + 255) / 256;
    const int gmsg = ((N + 7) / 8) * 8;

    // layer 0
    gemm128_mfma_kernel<false><<<g128, 512, 0, stream>>>(x, W0h, as0, ad0, hh, asr, adt, N);
    weight8_kernel<<<gw8, 256, 0, stream>>>(row_ptr, srcs, asr, adt, ew, inv, N);
    message128_kernel<<<gmsg, 256, 0, stream>>>(hh, row_ptr, srcs, ew, inv,
                                                b0, g0, bb0, m0, v0, feat, N);
    // layer 1
    gemm128_mfma_kernel<true><<<g128, 512, 0, stream>>>(feat, W1h, as1, ad1, hh, asr, adt, N);
    weight8_kernel<<<gw8, 256, 0, stream>>>(row_ptr, srcs, asr, adt, ew, inv, N);
    message128_kernel<<<gmsg, 256, 0, stream>>>(hh, row_ptr, srcs, ew, inv,
                                                b1, g1, bb1, m1, v1, feat, N);
    // layer 2
    gemm40_mfma_kernel<<<g64, 256, 0, stream>>>(feat, W2h, as2, ad2, h2, asr, adt, N);
    weight1_kernel<<<gw1, 256, 0, stream>>>(row_ptr, srcs, asr, adt, ew1, inv, N);
    message40_kernel<<<(N + 15) / 16, 256, 0, stream>>>(h2, row_ptr, srcs, ew1, inv,
                                                        b2, (float*)d_out, N);
}

// Round 19
// 213.083 us; speedup vs baseline: 1.8841x; 1.8841x over previous
//
#include <hip/hip_runtime.h>
#include <hip/hip_fp16.h>
#include <math.h>

constexpr float NEG_SLOPE = 0.2f;
constexpr float BN_EPS_C = 1e-5f;

using half8 = __attribute__((ext_vector_type(8))) _Float16;
using half4 = __attribute__((ext_vector_type(4))) _Float16;
using f32x4 = __attribute__((ext_vector_type(4))) float;

// ================= CSR build: LDS-binned two-level counting sort =================
// Edge packed as (d<<16)|s  (valid: N=50000 < 65536). bucket = d>>8.
// Block 0..NEB-1: histogram of 8192 edges.  Blocks NEB..NEB+63: weight fp16 cvt.

__global__ __launch_bounds__(256)
void hist_cvt_kernel(const int* __restrict__ ei, int* __restrict__ bucket_count,
                     int E, int N, int NEB,
                     const float* __restrict__ W0, const float* __restrict__ W1,
                     const float* __restrict__ W2,
                     __half* __restrict__ W0h, __half* __restrict__ W1h,
                     __half* __restrict__ W2h) {
    int t = threadIdx.x;
    if ((int)blockIdx.x >= NEB) {
        int i = ((int)blockIdx.x - NEB) * 256 + t;
        if (i < 16384) {
            W0h[i] = __float2half(W0[i]);
            W1h[i] = __float2half(W1[i]);
        }
        if (i < 6144) W2h[i] = __float2half(i < 5120 ? W2[i] : 0.f);
        return;
    }
    __shared__ int h[256];
    h[t] = 0;
    __syncthreads();
    int base = blockIdx.x * 8192;
    int ET = E + N;
#pragma unroll
    for (int q = 0; q < 32; ++q) {
        int i = base + q * 256 + t;
        if (i < ET) {
            int d = (i < E) ? ei[E + i] : (i - E);
            atomicAdd(&h[d >> 8], 1);
        }
    }
    __syncthreads();
    if (h[t] > 0) atomicAdd(&bucket_count[t], h[t]);
}

__global__ __launch_bounds__(256)
void bucket_scan_kernel(const int* __restrict__ bucket_count, int* __restrict__ bucket_ptr,
                        int* __restrict__ gcursor, int* __restrict__ row_ptr,
                        int N, int ET) {
    __shared__ int s[256];
    int t = threadIdx.x;
    int c = bucket_count[t];
    s[t] = c;
    __syncthreads();
    for (int off = 1; off < 256; off <<= 1) {
        int v = (t >= off) ? s[t - off] : 0;
        __syncthreads();
        s[t] += v;
        __syncthreads();
    }
    int excl = s[t] - c;
    bucket_ptr[t] = excl;
    gcursor[t] = excl;
    if (t == 255) {
        bucket_ptr[256] = s[255];
        row_ptr[N] = ET;
    }
}

__global__ __launch_bounds__(256)
void bucket_bin_kernel(const int* __restrict__ ei, int* __restrict__ gcursor,
                       unsigned* __restrict__ tmp, int E, int N) {
    __shared__ unsigned bins[8192];
    __shared__ int lcount[256];
    __shared__ int lofs[256];
    __shared__ int lbase[256];
    __shared__ int lcur[256];
    int t = threadIdx.x;
    lcount[t] = 0;
    __syncthreads();
    int base = blockIdx.x * 8192;
    int ET = E + N;
    unsigned pr[32];
#pragma unroll
    for (int q = 0; q < 32; ++q) {
        int i = base + q * 256 + t;
        pr[q] = 0xFFFFFFFFu;
        if (i < ET) {
            int s, d;
            if (i < E) { s = ei[i]; d = ei[E + i]; }
            else       { s = i - E; d = s; }
            pr[q] = ((unsigned)d << 16) | (unsigned)s;
            atomicAdd(&lcount[d >> 8], 1);
        }
    }
    __syncthreads();
    {
        int c = lcount[t];
        lofs[t] = c;
        __syncthreads();
        for (int off = 1; off < 256; off <<= 1) {
            int v = (t >= off) ? lofs[t - off] : 0;
            __syncthreads();
            lofs[t] += v;
            __syncthreads();
        }
        int excl = lofs[t] - c;
        __syncthreads();
        lofs[t] = excl;
        lcur[t] = excl;
        if (c > 0) lbase[t] = atomicAdd(&gcursor[t], c);
    }
    __syncthreads();
#pragma unroll
    for (int q = 0; q < 32; ++q) {
        if (pr[q] != 0xFFFFFFFFu) {
            int b = pr[q] >> 24;
            int p = atomicAdd(&lcur[b], 1);
            bins[p] = pr[q];
        }
    }
    __syncthreads();
    int total = min(8192, ET - base);
    for (int p = t; p < total; p += 256) {
        unsigned e = bins[p];
        int b = e >> 24;
        tmp[lbase[b] + (p - lofs[b])] = e;
    }
}

__global__ __launch_bounds__(256)
void fine_scatter_kernel(const unsigned* __restrict__ tmp, const int* __restrict__ bucket_ptr,
                         int* __restrict__ row_ptr, int* __restrict__ srcs, int N) {
    __shared__ int hist[256];
    __shared__ int scanb[256];
    __shared__ int cur[256];
    int b = blockIdx.x, t = threadIdx.x;
    int base = bucket_ptr[b];
    int cnt = bucket_ptr[b + 1] - base;
    int n0 = b << 8;
    hist[t] = 0;
    __syncthreads();
    for (int p = t; p < cnt; p += 256)
        atomicAdd(&hist[(int)(tmp[base + p] >> 16) - n0], 1);
    __syncthreads();
    int c = hist[t];
    scanb[t] = c;
    __syncthreads();
    for (int off = 1; off < 256; off <<= 1) {
        int v = (t >= off) ? scanb[t - off] : 0;
        __syncthreads();
        scanb[t] += v;
        __syncthreads();
    }
    int excl = scanb[t] - c;
    cur[t] = excl;
    if (n0 + t < N) row_ptr[n0 + t] = base + excl;
    __syncthreads();
    for (int p = t; p < cnt; p += 256) {
        unsigned e = tmp[base + p];
        int pos = atomicAdd(&cur[(int)(e >> 16) - n0], 1);
        srcs[base + pos] = (int)(e & 0xFFFFu);
    }
}

// ---------------- MFMA GEMM 128 (W in LDS, A direct): h(fp16) = X @ W^T + alphas ----------
// Block = 512 threads = 8 waves, 128 rows. C/D: col=lane&15, row=(lane>>4)*4+reg.

template<bool AHALF>
__global__ __launch_bounds__(512)
void gemm128_mfma_kernel(const void* __restrict__ Xv, const __half* __restrict__ W16,
                         const float* __restrict__ a_src, const float* __restrict__ a_dst,
                         __half* __restrict__ hp, float* __restrict__ asrc,
                         float* __restrict__ adst, int N) {
    __shared__ _Float16 Bs[128][136];
    const int t = threadIdx.x;
    const int n0 = blockIdx.x * 128;

#pragma unroll
    for (int i = 0; i < 4; ++i) {
        int lin = t + i * 512;
        int n = lin >> 4;
        int m = lin & 15;
        *reinterpret_cast<uint4*>(&Bs[n][8 * m]) =
            *reinterpret_cast<const uint4*>(&W16[(size_t)n * 128 + 8 * m]);
    }
    __syncthreads();

    const int l  = t & 63;
    const int w  = t >> 6;    // 0..7
    const int lr = l & 15;
    const int lg = l >> 4;
    const int rowA = n0 + 16 * w + lr;
    const bool rokA = rowA < N;

    f32x4 acc[8];
#pragma unroll
    for (int tt = 0; tt < 8; ++tt) acc[tt] = (f32x4){0.f, 0.f, 0.f, 0.f};

#pragma unroll
    for (int ks = 0; ks < 4; ++ks) {
        half8 a;
        if (rokA) {
            if constexpr (AHALF) {
                const __half* X = (const __half*)Xv;
                a = *reinterpret_cast<const half8*>(&X[(size_t)rowA * 128 + 8 * lg + 32 * ks]);
            } else {
                const float* X = (const float*)Xv;
                const float* p = &X[(size_t)rowA * 128 + 8 * lg + 32 * ks];
                float4 v0 = *reinterpret_cast<const float4*>(p);
                float4 v1 = *reinterpret_cast<const float4*>(p + 4);
                a[0] = (_Float16)v0.x; a[1] = (_Float16)v0.y;
                a[2] = (_Float16)v0.z; a[3] = (_Float16)v0.w;
                a[4] = (_Float16)v1.x; a[5] = (_Float16)v1.y;
                a[6] = (_Float16)v1.z; a[7] = (_Float16)v1.w;
            }
        } else {
#pragma unroll
            for (int q = 0; q < 8; ++q) a[q] = (_Float16)0.f;
        }
#pragma unroll
        for (int tt = 0; tt < 8; ++tt) {
            half8 b = *reinterpret_cast<const half8*>(&Bs[16 * tt + lr][8 * lg + 32 * ks]);
            acc[tt] = __builtin_amdgcn_mfma_f32_16x16x32_f16(a, b, acc[tt], 0, 0, 0);
        }
    }

    float av[8], bv[8];
#pragma unroll
    for (int tt = 0; tt < 8; ++tt) {
        av[tt] = a_src[16 * tt + lr];
        bv[tt] = a_dst[16 * tt + lr];
    }
#pragma unroll
    for (int reg = 0; reg < 4; ++reg) {
        int gr = n0 + 16 * w + 4 * lg + reg;
        bool ok = gr < N;
        if (ok) {
#pragma unroll
            for (int tt = 0; tt < 8; ++tt)
                hp[(size_t)gr * 128 + 16 * tt + lr] = __float2half(acc[tt][reg]);
        }
#pragma unroll
        for (int tt = 0; tt < 8; ++tt) {
            float p = acc[tt][reg] * av[tt];
            float q = acc[tt][reg] * bv[tt];
#pragma unroll
            for (int off = 1; off < 16; off <<= 1) {
                p += __shfl_xor(p, off, 16);
                q += __shfl_xor(q, off, 16);
            }
            if (ok && lr == tt) {
                asrc[(size_t)gr * 8 + tt] = p;
                adst[(size_t)gr * 8 + tt] = q;
            }
        }
    }
}

// ---------------- MFMA GEMM 40 (W in LDS, A direct): h2(fp16) = feat @ W2^T + alphas -------

__global__ __launch_bounds__(256)
void gemm40_mfma_kernel(const __half* __restrict__ X, const __half* __restrict__ W16,
                        const float* __restrict__ a_src, const float* __restrict__ a_dst,
                        __half* __restrict__ hp, float* __restrict__ asrc,
                        float* __restrict__ adst, int N) {
    __shared__ _Float16 Bs[48][136];
    const int t = threadIdx.x;
    const int n0 = blockIdx.x * 64;

#pragma unroll
    for (int i = 0; i < 3; ++i) {
        int lin = t + i * 256;
        if (lin < 768) {
            int n = lin >> 4;
            int m = lin & 15;
            *reinterpret_cast<uint4*>(&Bs[n][8 * m]) =
                *reinterpret_cast<const uint4*>(&W16[(size_t)n * 128 + 8 * m]);
        }
    }
    __syncthreads();

    const int l  = t & 63;
    const int w  = t >> 6;
    const int lr = l & 15;
    const int lg = l >> 4;
    const int rowA = n0 + 16 * w + lr;
    const bool rokA = rowA < N;

    f32x4 acc[3];
#pragma unroll
    for (int tt = 0; tt < 3; ++tt) acc[tt] = (f32x4){0.f, 0.f, 0.f, 0.f};

#pragma unroll
    for (int ks = 0; ks < 4; ++ks) {
        half8 a;
        if (rokA) {
            a = *reinterpret_cast<const half8*>(&X[(size_t)rowA * 128 + 8 * lg + 32 * ks]);
        } else {
#pragma unroll
            for (int q = 0; q < 8; ++q) a[q] = (_Float16)0.f;
        }
#pragma unroll
        for (int tt = 0; tt < 3; ++tt) {
            half8 b = *reinterpret_cast<const half8*>(&Bs[16 * tt + lr][8 * lg + 32 * ks]);
            acc[tt] = __builtin_amdgcn_mfma_f32_16x16x32_f16(a, b, acc[tt], 0, 0, 0);
        }
    }

    float av[3], bv[3];
#pragma unroll
    for (int tt = 0; tt < 3; ++tt) {
        int j = 16 * tt + lr;
        av[tt] = (j < 40) ? a_src[j] : 0.f;
        bv[tt] = (j < 40) ? a_dst[j] : 0.f;
    }
#pragma unroll
    for (int reg = 0; reg < 4; ++reg) {
        int gr = n0 + 16 * w + 4 * lg + reg;
        bool ok = gr < N;
        float p = 0.f, q = 0.f;
#pragma unroll
        for (int tt = 0; tt < 3; ++tt) {
            int j = 16 * tt + lr;
            if (ok && j < 40) hp[(size_t)gr * 40 + j] = __float2half(acc[tt][reg]);
            p += acc[tt][reg] * av[tt];
            q += acc[tt][reg] * bv[tt];
        }
#pragma unroll
        for (int off = 1; off < 16; off <<= 1) {
            p += __shfl_xor(p, off, 16);
            q += __shfl_xor(q, off, 16);
        }
        if (ok && lr == 0) {
            asrc[gr] = p;
            adst[gr] = q;
        }
    }
}

// ---------------- fused message + softmax, F=128, H=8, fp16 in/out ----------------
// 32 lanes/node; 16 lanes/edge, up to 4 edges in flight (2 per half).

__global__ __launch_bounds__(256)
void message128_kernel(const __half* __restrict__ hh, const int* __restrict__ row_ptr,
                       const int* __restrict__ srcs,
                       const float* __restrict__ asrc, const float* __restrict__ adst,
                       const float* __restrict__ bias,
                       const float* __restrict__ bn_g, const float* __restrict__ bn_b,
                       const float* __restrict__ bn_m, const float* __restrict__ bn_v,
                       __half* __restrict__ out16, int N) {
    int node = blockIdx.x * 8 + (threadIdx.x >> 5);
    if (node >= N) return;
    int tc = threadIdx.x & 31;
    int half_id = tc >> 4;
    int cl = tc & 15;
    int hd = cl >> 1;
    int beg = row_ptr[node], end = row_ptr[node + 1];
    float ad = adst[(size_t)node * 8 + hd];
    float ssum = 0.f;
    float acc[8];
#pragma unroll
    for (int q = 0; q < 8; ++q) acc[q] = 0.f;

    int j = beg;
    for (; j + 4 <= end; j += 4) {
        int sA = srcs[j + half_id];
        int sB = srcs[j + 2 + half_id];
        half8 vA = *reinterpret_cast<const half8*>(&hh[(size_t)sA * 128 + 8 * cl]);
        half8 vB = *reinterpret_cast<const half8*>(&hh[(size_t)sB * 128 + 8 * cl]);
        float eA = asrc[(size_t)sA * 8 + hd] + ad;
        float eB = asrc[(size_t)sB * 8 + hd] + ad;
        eA = (eA > 0.f) ? eA : NEG_SLOPE * eA;
        eB = (eB > 0.f) ? eB : NEG_SLOPE * eB;
        float wA = __expf(eA);
        float wB = __expf(eB);
        ssum += wA + wB;
#pragma unroll
        for (int q = 0; q < 8; ++q) {
            acc[q] = fmaf((float)vA[q], wA, acc[q]);
            acc[q] = fmaf((float)vB[q], wB, acc[q]);
        }
    }
    for (; j + 2 <= end; j += 2) {
        int s = srcs[j + half_id];
        half8 v = *reinterpret_cast<const half8*>(&hh[(size_t)s * 128 + 8 * cl]);
        float e = asrc[(size_t)s * 8 + hd] + ad;
        e = (e > 0.f) ? e : NEG_SLOPE * e;
        float wgt = __expf(e);
        ssum += wgt;
#pragma unroll
        for (int q = 0; q < 8; ++q) acc[q] = fmaf((float)v[q], wgt, acc[q]);
    }
    if (j < end && half_id == 0) {
        int s = srcs[j];
        half8 v = *reinterpret_cast<const half8*>(&hh[(size_t)s * 128 + 8 * cl]);
        float e = asrc[(size_t)s * 8 + hd] + ad;
        e = (e > 0.f) ? e : NEG_SLOPE * e;
        float wgt = __expf(e);
        ssum += wgt;
#pragma unroll
        for (int q = 0; q < 8; ++q) acc[q] = fmaf((float)v[q], wgt, acc[q]);
    }
    ssum += __shfl_xor(ssum, 16);
#pragma unroll
    for (int q = 0; q < 8; ++q) acc[q] += __shfl_xor(acc[q], 16);

    if (half_id == 0) {
        float inv = 1.0f / (ssum + 1e-16f);
        int c = cl * 8;
        float r[8];
#pragma unroll
        for (int pp = 0; pp < 2; ++pp) {
            int cc = c + 4 * pp;
            float4 bi = *reinterpret_cast<const float4*>(&bias[cc]);
            float4 g  = *reinterpret_cast<const float4*>(&bn_g[cc]);
            float4 bb = *reinterpret_cast<const float4*>(&bn_b[cc]);
            float4 mm = *reinterpret_cast<const float4*>(&bn_m[cc]);
            float4 vv = *reinterpret_cast<const float4*>(&bn_v[cc]);
            r[4 * pp + 0] = (acc[4 * pp + 0] * inv + bi.x - mm.x) * rsqrtf(vv.x + BN_EPS_C) * g.x + bb.x;
            r[4 * pp + 1] = (acc[4 * pp + 1] * inv + bi.y - mm.y) * rsqrtf(vv.y + BN_EPS_C) * g.y + bb.y;
            r[4 * pp + 2] = (acc[4 * pp + 2] * inv + bi.z - mm.z) * rsqrtf(vv.z + BN_EPS_C) * g.z + bb.z;
            r[4 * pp + 3] = (acc[4 * pp + 3] * inv + bi.w - mm.w) * rsqrtf(vv.w + BN_EPS_C) * g.w + bb.w;
        }
        half8 o;
#pragma unroll
        for (int q = 0; q < 8; ++q) {
            float rv = (r[q] > 0.f) ? r[q] : expm1f(r[q]);
            o[q] = (_Float16)rv;
        }
        *reinterpret_cast<half8*>(&out16[(size_t)node * 128 + c]) = o;
    }
}

// ---------------- fused message + softmax, F=40, H=1, fp16 gather ----------------

__global__ __launch_bounds__(256)
void message40_kernel(const __half* __restrict__ hh2, const int* __restrict__ row_ptr,
                      const int* __restrict__ srcs,
                      const float* __restrict__ asrc, const float* __restrict__ adst,
                      const float* __restrict__ b2, float* __restrict__ out, int N) {
    int node = blockIdx.x * 16 + (threadIdx.x >> 4);
    if (node >= N) return;
    int tc = threadIdx.x & 15;
    int beg = row_ptr[node], end = row_ptr[node + 1];
    float ad = adst[node];
    float ssum = 0.f;
    float acc[4] = {0.f, 0.f, 0.f, 0.f};
    int j = beg;
    for (; j + 2 <= end; j += 2) {
        int s0 = srcs[j];
        int s1 = srcs[j + 1];
        half4 v0 = (half4){0, 0, 0, 0}, v1 = (half4){0, 0, 0, 0};
        if (tc < 10) {
            v0 = *reinterpret_cast<const half4*>(&hh2[(size_t)s0 * 40 + 4 * tc]);
            v1 = *reinterpret_cast<const half4*>(&hh2[(size_t)s1 * 40 + 4 * tc]);
        }
        float e0 = asrc[s0] + ad;
        float e1 = asrc[s1] + ad;
        e0 = (e0 > 0.f) ? e0 : NEG_SLOPE * e0;
        e1 = (e1 > 0.f) ? e1 : NEG_SLOPE * e1;
        float w0 = __expf(e0);
        float w1 = __expf(e1);
        ssum += w0 + w1;
#pragma unroll
        for (int q = 0; q < 4; ++q) {
            acc[q] = fmaf((float)v0[q], w0, acc[q]);
            acc[q] = fmaf((float)v1[q], w1, acc[q]);
        }
    }
    if (j < end) {
        int s0 = srcs[j];
        half4 v0 = (half4){0, 0, 0, 0};
        if (tc < 10) v0 = *reinterpret_cast<const half4*>(&hh2[(size_t)s0 * 40 + 4 * tc]);
        float e0 = asrc[s0] + ad;
        e0 = (e0 > 0.f) ? e0 : NEG_SLOPE * e0;
        float w0 = __expf(e0);
        ssum += w0;
#pragma unroll
        for (int q = 0; q < 4; ++q) acc[q] = fmaf((float)v0[q], w0, acc[q]);
    }
    if (tc < 10) {
        float inv = 1.0f / (ssum + 1e-16f);
        int c = tc * 4;
        float4 bi = *reinterpret_cast<const float4*>(&b2[c]);
        *reinterpret_cast<float4*>(&out[(size_t)node * 40 + c]) =
            make_float4(acc[0] * inv + bi.x, acc[1] * inv + bi.y,
                        acc[2] * inv + bi.z, acc[3] * inv + bi.w);
    }
}

// ---------------- launcher ----------------

static inline char* align256(char* p) {
    return (char*)(((uintptr_t)p + 255) & ~(uintptr_t)255);
}

extern "C" void kernel_launch(void* const* d_in, const int* in_sizes, int n_in,
                              void* d_out, int out_size, void* d_ws, size_t ws_size,
                              hipStream_t stream) {
    const float* x   = (const float*)d_in[0];
    const int*   ei  = (const int*)d_in[1];
    const float* W0  = (const float*)d_in[2];
    const float* as0 = (const float*)d_in[3];
    const float* ad0 = (const float*)d_in[4];
    const float* b0  = (const float*)d_in[5];
    const float* g0  = (const float*)d_in[6];
    const float* bb0 = (const float*)d_in[7];
    const float* m0  = (const float*)d_in[8];
    const float* v0  = (const float*)d_in[9];
    const float* W1  = (const float*)d_in[10];
    const float* as1 = (const float*)d_in[11];
    const float* ad1 = (const float*)d_in[12];
    const float* b1  = (const float*)d_in[13];
    const float* g1  = (const float*)d_in[14];
    const float* bb1 = (const float*)d_in[15];
    const float* m1  = (const float*)d_in[16];
    const float* v1  = (const float*)d_in[17];
    const float* W2  = (const float*)d_in[18];
    const float* as2 = (const float*)d_in[19];
    const float* ad2 = (const float*)d_in[20];
    const float* b2  = (const float*)d_in[21];

    const int N  = in_sizes[0] / 128;
    const int E  = in_sizes[1] / 2;
    const int ET = E + N;
    const int NBUK = (N + 255) >> 8;
    const int NEB  = (ET + 8191) / 8192;

    char* wsp = (char*)d_ws;
    int* bucket_count = (int*)wsp;  wsp = align256(wsp + 256 * 4);
    int* bucket_ptr   = (int*)wsp;  wsp = align256(wsp + 257 * 4);
    int* gcursor      = (int*)wsp;  wsp = align256(wsp + 256 * 4);
    int* row_ptr      = (int*)wsp;  wsp = align256(wsp + (size_t)(N + 1) * 4);
    unsigned* tmp     = (unsigned*)wsp; wsp = align256(wsp + (size_t)ET * 4);
    int* srcs         = (int*)wsp;  wsp = align256(wsp + (size_t)ET * 4);
    __half* hh        = (__half*)wsp; wsp = align256(wsp + (size_t)N * 128 * 2);
    __half* h2        = (__half*)wsp; wsp = align256(wsp + (size_t)N * 40 * 2);
    __half* feat      = (__half*)wsp; wsp = align256(wsp + (size_t)N * 128 * 2);
    float* asr        = (float*)wsp;  wsp = align256(wsp + (size_t)N * 8 * 4);
    float* adt        = (float*)wsp;  wsp = align256(wsp + (size_t)N * 8 * 4);
    __half* W0h       = (__half*)wsp; wsp = align256(wsp + 16384 * 2);
    __half* W1h       = (__half*)wsp; wsp = align256(wsp + 16384 * 2);
    __half* W2h       = (__half*)wsp; wsp = align256(wsp + 6144 * 2);

    // CSR build + weight cvt (merged first launch)
    hipMemsetAsync(bucket_count, 0, 256 * 4, stream);
    hist_cvt_kernel<<<NEB + 64, 256, 0, stream>>>(ei, bucket_count, E, N, NEB,
                                                  W0, W1, W2, W0h, W1h, W2h);
    bucket_scan_kernel<<<1, 256, 0, stream>>>(bucket_count, bucket_ptr, gcursor, row_ptr, N, ET);
    bucket_bin_kernel<<<NEB, 256, 0, stream>>>(ei, gcursor, tmp, E, N);
    fine_scatter_kernel<<<NBUK, 256, 0, stream>>>(tmp, bucket_ptr, row_ptr, srcs, N);

    const int g128 = (N + 127) / 128;
    const int g64  = (N + 63) / 64;

    // layer 0: x (fp32) -> feat (fp16)
    gemm128_mfma_kernel<false><<<g128, 512, 0, stream>>>(x, W0h, as0, ad0, hh, asr, adt, N);
    message128_kernel<<<(N + 7) / 8, 256, 0, stream>>>(hh, row_ptr, srcs, asr, adt,
                                                       b0, g0, bb0, m0, v0, feat, N);
    // layer 1: feat (fp16) -> feat (fp16)
    gemm128_mfma_kernel<true><<<g128, 512, 0, stream>>>(feat, W1h, as1, ad1, hh, asr, adt, N);
    message128_kernel<<<(N + 7) / 8, 256, 0, stream>>>(hh, row_ptr, srcs, asr, adt,
                                                       b1, g1, bb1, m1, v1, feat, N);
    // layer 2: feat -> d_out
    gemm40_mfma_kernel<<<g64, 256, 0, stream>>>(feat, W2h, as2, ad2, h2, asr, adt, N);
    message40_kernel<<<(N + 15) / 16, 256, 0, stream>>>(h2, row_ptr, srcs,
                                                        asr, adt, b2, (float*)d_out, N);
}